// Round 4
// baseline (747.480 us; speedup 1.0000x reference)
//
#include <hip/hip_runtime.h>
#include <hip/hip_bf16.h>

#define TPB 256
#define NCODES 1024
#define DIMS 256
#define PIXB 64
#define XPAD 264      // xs row stride in ushorts: 528 B = 33*16, px-stride ≡ 4 banks -> 2-way (free)
#define DELTA 3.0f    // screening margin; bf16 dot error worst-case ~1.3
#define CAP 10        // candidates per pixel; overflow -> exact full rescan

typedef __attribute__((ext_vector_type(8))) short bf16x8;
typedef __attribute__((ext_vector_type(4))) float f32x4;

// order-preserving float->uint map (works for negatives) for atomicMin
__device__ __forceinline__ unsigned fkey(float f) {
    unsigned u = __float_as_uint(f);
    return (u & 0x80000000u) ? ~u : (u | 0x80000000u);
}
__device__ __forceinline__ float funkey(unsigned k) {
    return (k & 0x80000000u) ? __uint_as_float(k & 0x7fffffffu) : __uint_as_float(~k);
}

// prep: ebs = bf16(emb) pre-swizzled into MFMA A-fragment order; e2 = exact fp32 row norms.
// A-frag layout: unit(ct, kc, lane) at ((ct*8 + kc)*64 + lane)*8 ushorts,
// lane = q*16 + col holds code ct*16+col, dims kc*32 + q*8 .. +7.
__global__ __launch_bounds__(64) void prep_kernel(const float* __restrict__ emb,
                                                  ushort* __restrict__ ebs,
                                                  float* __restrict__ e2) {
    const int c = blockIdx.x;
    const int l = threadIdx.x;           // lane l holds dims 4l..4l+3
    float4 v = *(const float4*)(emb + (size_t)c * DIMS + 4 * l);
    __hip_bfloat16 h0 = __float2bfloat16(v.x), h1 = __float2bfloat16(v.y);
    __hip_bfloat16 h2 = __float2bfloat16(v.z), h3 = __float2bfloat16(v.w);
    ushort4 u;
    u.x = *(ushort*)&h0; u.y = *(ushort*)&h1; u.z = *(ushort*)&h2; u.w = *(ushort*)&h3;
    // dims 4l..4l+3: kc = l>>3, q = (l>>1)&3, j0 = (l&1)*4
    int idx = ((((c >> 4) * 8 + (l >> 3)) * 64) + ((l >> 1) & 3) * 16 + (c & 15)) * 8 + (l & 1) * 4;
    *(ushort4*)(ebs + idx) = u;
    float s = v.x * v.x + v.y * v.y + v.z * v.z + v.w * v.w;
#pragma unroll
    for (int off = 1; off < 64; off <<= 1) s += __shfl_xor(s, off);
    if (l == 0) e2[c] = s;
}

__global__ __launch_bounds__(TPB, 4) void vq_kernel(const float* __restrict__ z,
                                                    const float* __restrict__ emb,
                                                    const ushort* __restrict__ ebs,
                                                    const float* __restrict__ e2g,
                                                    int* __restrict__ out) {
    // 33792 + 4096 + 256 + 256 + 2560 = 40960 B -> 4 blocks/CU (160 KiB LDS)
    __shared__ __align__(16) ushort xs[PIXB * XPAD];   // bf16 x, [px][dim]
    __shared__ float    e2s[NCODES];
    __shared__ unsigned minkey[PIXB];
    __shared__ int      cnt[PIXB];
    __shared__ int      cand[PIXB * CAP];

    const int tid = threadIdx.x;
    const int w   = tid >> 6;     // wave 0..3
    const int L   = tid & 63;
    const int col = L & 15;       // MFMA col (pixel within n-tile)
    const int q   = L >> 4;       // MFMA quad
    const int pixbase = blockIdx.x * PIXB;
    const int t  = pixbase >> 12;
    const int n0 = pixbase & 4095;

    // ---- phase 1: coalesced z load (float4 over px), bf16 transpose into LDS ----
    {
        const int pq = L & 15;    // which float4 of the 64-px row
        const int dq = L >> 4;    // dim within group of 4
#pragma unroll
        for (int i = 0; i < 16; ++i) {
            const int d = w * 64 + i * 4 + dq;
            const float4 v = *(const float4*)(z + (((size_t)(t * DIMS + d)) << 12) + n0 + 4 * pq);
            __hip_bfloat16 h0 = __float2bfloat16(v.x), h1 = __float2bfloat16(v.y);
            __hip_bfloat16 h2 = __float2bfloat16(v.z), h3 = __float2bfloat16(v.w);
            xs[(4 * pq + 0) * XPAD + d] = *(ushort*)&h0;
            xs[(4 * pq + 1) * XPAD + d] = *(ushort*)&h1;
            xs[(4 * pq + 2) * XPAD + d] = *(ushort*)&h2;
            xs[(4 * pq + 3) * XPAD + d] = *(ushort*)&h3;
        }
    }
#pragma unroll
    for (int i = 0; i < 4; ++i) e2s[tid + 256 * i] = e2g[tid + 256 * i];
    if (tid < 64) { minkey[tid] = 0xFFFFFFFFu; cnt[tid] = 0; }
    __syncthreads();

    // ---- phase 2: barrier-free MFMA K-loop; af straight from global (L2-hot) ----
#pragma unroll 1
    for (int cc = 0; cc < 4; ++cc) {
        f32x4 acc[4][4];
#pragma unroll
        for (int mt = 0; mt < 4; ++mt)
#pragma unroll
            for (int nt = 0; nt < 4; ++nt) acc[mt][nt] = (f32x4){0.f, 0.f, 0.f, 0.f};

#pragma unroll 1
        for (int kc = 0; kc < 8; ++kc) {
            bf16x8 af[4];
            const ushort* ap = ebs + ((((size_t)(cc * 16 + w * 4) * 8) + kc) * 64 + L) * 8;
#pragma unroll
            for (int mt = 0; mt < 4; ++mt)
                af[mt] = *(const bf16x8*)(ap + mt * 4096);   // mt stride = 8*64*8 ushorts
            bf16x8 bfr[4];
#pragma unroll
            for (int nt = 0; nt < 4; ++nt)
                bfr[nt] = *(const bf16x8*)&xs[(nt * 16 + col) * XPAD + kc * 32 + q * 8];
#pragma unroll
            for (int mt = 0; mt < 4; ++mt)
#pragma unroll
                for (int nt = 0; nt < 4; ++nt)
                    acc[mt][nt] = __builtin_amdgcn_mfma_f32_16x16x32_bf16(
                        af[mt], bfr[nt], acc[mt][nt], 0, 0, 0);
        }

        // epilogue: s = e2[c] - 2*dot ; C layout col=px, row=q*4+r
        f32x4 e2r[4];
#pragma unroll
        for (int mt = 0; mt < 4; ++mt)
            e2r[mt] = *(const f32x4*)&e2s[cc * 256 + w * 64 + mt * 16 + q * 4];
#pragma unroll
        for (int nt = 0; nt < 4; ++nt) {
            float m = 3.4e38f;
#pragma unroll
            for (int mt = 0; mt < 4; ++mt)
#pragma unroll
                for (int r = 0; r < 4; ++r)
                    m = fminf(m, e2r[mt][r] - 2.f * acc[mt][nt][r]);
            atomicMin(&minkey[nt * 16 + col], fkey(m));
        }
        __syncthreads();
#pragma unroll
        for (int nt = 0; nt < 4; ++nt) {
            const int px = nt * 16 + col;
            const float thr = funkey(minkey[px]) + DELTA;
#pragma unroll
            for (int mt = 0; mt < 4; ++mt)
#pragma unroll
                for (int r = 0; r < 4; ++r) {
                    float s = e2r[mt][r] - 2.f * acc[mt][nt][r];
                    if (s <= thr) {
                        int pos = atomicAdd(&cnt[px], 1);
                        if (pos < CAP)
                            cand[px * CAP + pos] = cc * 256 + w * 64 + mt * 16 + q * 4 + r;
                    }
                }
        }
    }
    __syncthreads();

    // ---- phase 3: exact fp32 rescore; wave w handles px w*16..+15 ----
#pragma unroll 1
    for (int pi = 0; pi < 16; ++pi) {
        const int px = w * 16 + pi;
        const int n  = cnt[px];
        const float* zp = z + (((size_t)t * DIMS + 4 * L) << 12) + n0 + px;
        float x0 = zp[0];
        float x1 = zp[(size_t)1 << 12];
        float x2 = zp[(size_t)2 << 12];
        float x3 = zp[(size_t)3 << 12];
        float bs = 3.4e38f;
        int   bi = 0;
        if (n <= CAP) {
            for (int k = 0; k < n; ++k) {
                int c = cand[px * CAP + k];
                float4 ev = *(const float4*)(emb + (size_t)c * DIMS + 4 * L);
                float p = x0 * ev.x + x1 * ev.y + x2 * ev.z + x3 * ev.w;
#pragma unroll
                for (int off = 1; off < 64; off <<= 1) p += __shfl_xor(p, off);
                float s = e2s[c] - 2.f * p;
                if (s < bs || (s == bs && c < bi)) { bs = s; bi = c; }
            }
        } else {
            // overflow fallback (rare): exact scan of all codes
            for (int c = 0; c < NCODES; ++c) {
                float4 ev = *(const float4*)(emb + (size_t)c * DIMS + 4 * L);
                float p = x0 * ev.x + x1 * ev.y + x2 * ev.z + x3 * ev.w;
#pragma unroll
                for (int off = 1; off < 64; off <<= 1) p += __shfl_xor(p, off);
                float s = e2s[c] - 2.f * p;
                if (s < bs || (s == bs && c < bi)) { bs = s; bi = c; }
            }
        }
        if (L == 0) out[pixbase + px] = bi;
    }
}

extern "C" void kernel_launch(void* const* d_in, const int* in_sizes, int n_in,
                              void* d_out, int out_size, void* d_ws, size_t ws_size,
                              hipStream_t stream) {
    const float* z   = (const float*)d_in[0];   // (16,256,64,64) fp32
    const float* emb = (const float*)d_in[1];   // (1024,256) fp32
    int* out = (int*)d_out;                     // (16,64,64) int32

    ushort* ebs = (ushort*)d_ws;                                         // 512 KB swizzled bf16
    float*  e2  = (float*)((char*)d_ws + (size_t)NCODES * DIMS * sizeof(ushort)); // 4 KB

    prep_kernel<<<NCODES, 64, 0, stream>>>(emb, ebs, e2);
    vq_kernel<<<(16 * 64 * 64) / PIXB, TPB, 0, stream>>>(z, emb, ebs, e2, out);
}